// Round 1
// 926.162 us; speedup vs baseline: 1.0976x; 1.0976x over previous
//
#include <hip/hip_runtime.h>

#define DEV __device__ __forceinline__

typedef __attribute__((ext_vector_type(8))) short s16x8;   // 8 bf16 (4 VGPRs) MFMA A/B frag
typedef __attribute__((ext_vector_type(4))) float f32x4;   // MFMA C/D frag
typedef __attribute__((ext_vector_type(4))) unsigned short u16x4;

#define BTOK 8192   // B*S
#define DD   1024
#define FF   4096
#define EE   4
#define BK   32     // K-step per ring slot

// round-to-nearest-even f32 -> bf16 bits
DEV unsigned short f2bf(float f) {
  unsigned int u = __float_as_uint(f);
  unsigned int r = (u + 0x7FFFu + ((u >> 16) & 1u)) >> 16;
  return (unsigned short)r;
}

// async global->LDS, 16 bytes/lane. LDS dest must be wave-uniform base + lane*16.
DEV void gld_lds16(const void* g, void* l) {
  __builtin_amdgcn_global_load_lds(
      (const __attribute__((address_space(1))) unsigned int*)g,
      (__attribute__((address_space(3))) unsigned int*)l,
      16, 0, 0);
}

// ---------------------------------------------------------------------------
// 128x128 bf16 MFMA tile mainloop, 4-slot LDS ring, counted vmcnt (T3+T4),
// XOR-swizzled LDS (T2), setprio around MFMA (T5).
// A: [M][K] row-major bf16. B: [N][K] row-major (B^T, K contiguous).
// 256 threads = 4 waves (2x2); each wave owns 64x64 = 4x4 16x16x32 tiles.
// LDS: As/Bs each 4 slots x [128][BK] = 32 KB -> 64 KB total (2 blocks/CU).
//
// Swizzle: within a 64-B row, colbyte ^= (row&3)<<4 (involution, 16-B granular).
// global_load_lds writes LINEAR dest; the SOURCE address is pre-swizzled, and
// reads apply the same XOR (rule: both-sides-or-neither).
//
// Ring schedule per K-tile kt (slot = kt&3):
//   issue STAGE(kt+2)  -> slot (kt+2)&3        (4 gld_lds, 16B/lane)
//   s_waitcnt vmcnt(8)                          (STAGE(kt) landed; kt+1,kt+2 in flight)
//   s_barrier                                   (all waves' STAGE(kt) visible)
//   12x ds_read_b128 + 16x MFMA from slot kt&3
// One barrier per K-tile; vmcnt never drains to 0 until the tail.
// Safety: slot s=(kt+2)&3 was last READ in iteration kt-2, which every wave
// finished before barrier(kt-1); the STAGE(kt+2) issue is after barrier(kt-1).
// Requires NT % 4 == 0 when called repeatedly (holds: 1024/32, 4096/32).
// ---------------------------------------------------------------------------
DEV void gemm_ring(const unsigned short* __restrict__ A,
                   const unsigned short* __restrict__ B,
                   int K, int tileM, int tileN,
                   unsigned short* As, unsigned short* Bs,
                   f32x4 (&acc)[4][4]) {
  const int t    = threadIdx.x;
  const int lane = t & 63;
  const int wv   = t >> 6;
  const int wm   = (wv & 1) << 6;
  const int wn   = (wv >> 1) << 6;
  const int m16  = lane & 15;
  const int q    = lane >> 4;

  // ---- staging addresses (thread-constant) ----
  // linear LDS byte (within slot) o = j*4096 + t*16  ->  row = j*64 + (t>>2),
  // colbyte' = (t&3)*16. Element stored there is logical colbyte' ^ ((row&3)<<4).
  const int rT   = t >> 2;                         // 0..63 (j adds 64; row&3 unchanged)
  const int sKey = (rT & 3) << 4;                  // swizzle key, bytes
  const int cSrc = ((((t & 3) << 4) ^ sKey) >> 1); // source col offset, elems
  const unsigned short* Arow = A + (size_t)(tileM + rT) * K + cSrc;
  const unsigned short* Brow = B + (size_t)(tileN + rT) * K + cSrc;
  const int ldsOff = t * 8;                        // shorts: linear dest, lane*16B

  // ---- fragment-read addresses (lane-constant) ----
  // logical (row r, colbyte q*16) lives at position colbyte q*16 ^ ((r&3)<<4)
  const int rKey = (m16 & 3) << 4;
  const int cOff = (((q << 4) ^ rKey) >> 1);       // shorts
  const int aRd  = (wm + m16) * BK + cOff;
  const int bRd  = (wn + m16) * BK + cOff;

  const int NT = K / BK;

#define STAGE(kt_)                                                            \
  {                                                                           \
    const int s_  = ((kt_) & 3) * (128 * BK);                                 \
    const int ko_ = (kt_) * BK;                                               \
    gld_lds16(Arow + ko_,                  As + s_ + ldsOff);                 \
    gld_lds16(Arow + (size_t)64 * K + ko_, As + s_ + 64 * BK + ldsOff);       \
    gld_lds16(Brow + ko_,                  Bs + s_ + ldsOff);                 \
    gld_lds16(Brow + (size_t)64 * K + ko_, Bs + s_ + 64 * BK + ldsOff);       \
  }

  STAGE(0);
  STAGE(1);

  for (int kt = 0; kt < NT; ++kt) {
    if (kt + 2 < NT) {
      STAGE(kt + 2);
      asm volatile("s_waitcnt vmcnt(8)" ::: "memory");   // counted: 2 stages in flight
    } else if (kt + 1 < NT) {
      asm volatile("s_waitcnt vmcnt(4)" ::: "memory");   // tail-1
    } else {
      asm volatile("s_waitcnt vmcnt(0)" ::: "memory");   // tail drain
    }
    __builtin_amdgcn_s_barrier();
    asm volatile("" ::: "memory");   // fence: no LDS read hoists above barrier

    const int sb = (kt & 3) * (128 * BK);
    s16x8 aF[4], bF[4];
#pragma unroll
    for (int i = 0; i < 4; ++i) {
      aF[i] = *(const s16x8*)(As + sb + aRd + i * (16 * BK));
      bF[i] = *(const s16x8*)(Bs + sb + bRd + i * (16 * BK));
    }
    __builtin_amdgcn_s_setprio(1);
#pragma unroll
    for (int mt = 0; mt < 4; ++mt)
#pragma unroll
      for (int nt = 0; nt < 4; ++nt)
        acc[mt][nt] = __builtin_amdgcn_mfma_f32_16x16x32_bf16(
            aF[mt], bF[nt], acc[mt][nt], 0, 0, 0);
    __builtin_amdgcn_s_setprio(0);
  }
#undef STAGE
}

// ---------------------------------------------------------------------------
// GEMM1: h[slot][t][f] = bf16( c[t,e] * relu( x[t]@W1[e] + b1[e][f] ) )
// ---------------------------------------------------------------------------
__global__ __launch_bounds__(256, 2) void gemm1_kernel(
    const unsigned short* __restrict__ xb,   // [BTOK][DD]
    const unsigned short* __restrict__ W1T,  // [EE][FF][DD]
    const float* __restrict__ b1,            // [EE][FF]
    const float* __restrict__ c,             // [BTOK][EE]
    unsigned short* __restrict__ h,          // [slots][BTOK][FF]
    int eBase) {
  __shared__ __attribute__((aligned(16))) unsigned short As[4 * 128 * BK];
  __shared__ __attribute__((aligned(16))) unsigned short Bs[4 * 128 * BK];

  // XCD-aware bijective swizzle: nwg = 32*64 = 2048, 8 XCDs -> chunk 256
  const int bid = blockIdx.y * 32 + blockIdx.x;
  const int swz = (bid & 7) * 256 + (bid >> 3);
  const int tileN = (swz & 31) * 128;
  const int tileM = (swz >> 5) * 128;

  const int e = eBase + blockIdx.z;

  f32x4 acc[4][4];
#pragma unroll
  for (int i = 0; i < 4; ++i)
#pragma unroll
    for (int j = 0; j < 4; ++j) acc[i][j] = f32x4{0.f, 0.f, 0.f, 0.f};

  gemm_ring(xb, W1T + (size_t)e * FF * DD, DD, tileM, tileN, As, Bs, acc);

  const int t = threadIdx.x;
  const int lane = t & 63, wv = t >> 6;
  const int wm = (wv & 1) << 6, wn = (wv >> 1) << 6;
  const int m16 = lane & 15, quad = lane >> 4;
  const float* b1e = b1 + e * FF;
  unsigned short* hs = h + (size_t)blockIdx.z * ((size_t)BTOK * FF);

#pragma unroll
  for (int mt = 0; mt < 4; ++mt) {
    const int row = tileM + wm + mt * 16 + quad * 4;   // C/D: row = quad*4 + reg
    const float cv0 = c[(row + 0) * EE + e];
    const float cv1 = c[(row + 1) * EE + e];
    const float cv2 = c[(row + 2) * EE + e];
    const float cv3 = c[(row + 3) * EE + e];
#pragma unroll
    for (int nt = 0; nt < 4; ++nt) {
      const int col = tileN + wn + nt * 16 + m16;      // C/D: col = lane&15
      const float bb = b1e[col];
      f32x4 v = acc[mt][nt];
      hs[(size_t)(row + 0) * FF + col] = f2bf(fmaxf(v[0] + bb, 0.f) * cv0);
      hs[(size_t)(row + 1) * FF + col] = f2bf(fmaxf(v[1] + bb, 0.f) * cv1);
      hs[(size_t)(row + 2) * FF + col] = f2bf(fmaxf(v[2] + bb, 0.f) * cv2);
      hs[(size_t)(row + 3) * FF + col] = f2bf(fmaxf(v[3] + bb, 0.f) * cv3);
    }
  }
}

// ---------------------------------------------------------------------------
// GEMM2: out[t][d] += sum_{ei<eCount} h[ei][t]@W2[eBase+ei]
// (out pre-initialized with b2 term; accumulator carries across experts)
// ---------------------------------------------------------------------------
__global__ __launch_bounds__(256, 2) void gemm2_kernel(
    const unsigned short* __restrict__ h,    // [eCount][BTOK][FF]
    const unsigned short* __restrict__ W2T,  // [EE][DD][FF]
    float* __restrict__ out,                 // [BTOK][DD]
    int eBase, int eCount) {
  __shared__ __attribute__((aligned(16))) unsigned short As[4 * 128 * BK];
  __shared__ __attribute__((aligned(16))) unsigned short Bs[4 * 128 * BK];

  // nwg = 8*64 = 512, chunk 64
  const int bid = blockIdx.y * 8 + blockIdx.x;
  const int swz = (bid & 7) * 64 + (bid >> 3);
  const int tileN = (swz & 7) * 128;
  const int tileM = (swz >> 3) * 128;

  f32x4 acc[4][4];
#pragma unroll
  for (int i = 0; i < 4; ++i)
#pragma unroll
    for (int j = 0; j < 4; ++j) acc[i][j] = f32x4{0.f, 0.f, 0.f, 0.f};

  for (int ei = 0; ei < eCount; ++ei)
    gemm_ring(h + (size_t)ei * BTOK * FF,
              W2T + (size_t)(eBase + ei) * DD * FF,
              FF, tileM, tileN, As, Bs, acc);

  const int t = threadIdx.x;
  const int lane = t & 63, wv = t >> 6;
  const int wm = (wv & 1) << 6, wn = (wv >> 1) << 6;
  const int m16 = lane & 15, quad = lane >> 4;

#pragma unroll
  for (int mt = 0; mt < 4; ++mt) {
    const int row = tileM + wm + mt * 16 + quad * 4;
#pragma unroll
    for (int nt = 0; nt < 4; ++nt) {
      const int col = tileN + wn + nt * 16 + m16;
      f32x4 v = acc[mt][nt];
      out[(size_t)(row + 0) * DD + col] += v[0];
      out[(size_t)(row + 1) * DD + col] += v[1];
      out[(size_t)(row + 2) * DD + col] += v[2];
      out[(size_t)(row + 3) * DD + col] += v[3];
    }
  }
}

// ---------------------------------------------------------------------------
// Per-token: u = sigmoid(x.Wu + bu); c[t,e] = (i<=k)? u/i : 0, i=((e-s)&3)+1;
// out[t,:] = sum_e c[t,e]*b2[e,:]   (b2 term / accumulator init)
// ---------------------------------------------------------------------------
__global__ __launch_bounds__(256) void u_kernel(
    const float* __restrict__ x,   // [BTOK][DD]
    const float* __restrict__ Wu,  // [DD]
    const float* __restrict__ bu,  // [1]
    const float* __restrict__ b2,  // [EE][DD]
    float* __restrict__ c,         // [BTOK][EE]
    float* __restrict__ out) {     // [BTOK][DD]
  const int tok = blockIdx.x;
  const int tid = threadIdx.x;
  const float* xr = x + (size_t)tok * DD;

  f32x4 xv = ((const f32x4*)xr)[tid];
  f32x4 wv = ((const f32x4*)Wu)[tid];
  float s = xv[0] * wv[0] + xv[1] * wv[1] + xv[2] * wv[2] + xv[3] * wv[3];
#pragma unroll
  for (int off = 32; off > 0; off >>= 1) s += __shfl_down(s, off);

  __shared__ float red[4];
  __shared__ float cL[4];
  if ((tid & 63) == 0) red[tid >> 6] = s;
  __syncthreads();
  if (tid == 0) {
    float dot = red[0] + red[1] + red[2] + red[3] + bu[0];
    float u = 1.f / (1.f + expf(-dot));
    float kf = ceilf(u * 4.f);
    kf = fminf(fmaxf(kf, 1.f), 4.f);
    int k = (int)kf;
    int s4 = tok & 3;  // S=2048 divisible by 4 -> s%4 == tok%4
#pragma unroll
    for (int e = 0; e < EE; ++e) {
      int i = ((e - s4) & 3) + 1;
      float ce = (i <= k) ? (u / (float)i) : 0.f;
      cL[e] = ce;
      c[tok * EE + e] = ce;
    }
  }
  __syncthreads();
  const float c0 = cL[0], c1 = cL[1], c2 = cL[2], c3 = cL[3];
#pragma unroll
  for (int d = tid; d < DD; d += 256)
    out[(size_t)tok * DD + d] =
        c0 * b2[d] + c1 * b2[DD + d] + c2 * b2[2 * DD + d] + c3 * b2[3 * DD + d];
}

// ---------------------------------------------------------------------------
// f32 -> bf16 convert (4 elems/thread)
// ---------------------------------------------------------------------------
__global__ __launch_bounds__(256) void cvt_kernel(const float* __restrict__ in,
                                                  unsigned short* __restrict__ ob,
                                                  int n4) {
  int i = blockIdx.x * 256 + threadIdx.x;
  if (i >= n4) return;
  f32x4 a = ((const f32x4*)in)[i];
  u16x4 o = {f2bf(a[0]), f2bf(a[1]), f2bf(a[2]), f2bf(a[3])};
  ((u16x4*)ob)[i] = o;
}

// ---------------------------------------------------------------------------
// Transpose-convert: src [E][R][C] f32 -> dst [E][C][R] bf16. 32x32 LDS tiles.
// ---------------------------------------------------------------------------
__global__ __launch_bounds__(256) void tpose_kernel(const float* __restrict__ src,
                                                    unsigned short* __restrict__ dst,
                                                    int R, int C) {
  __shared__ float tile[32][33];
  const int e = blockIdx.z;
  const int r0 = blockIdx.y * 32, c0 = blockIdx.x * 32;
  const int tx = threadIdx.x & 31, ty = threadIdx.x >> 5;
  const float* s = src + (size_t)e * R * C;
  unsigned short* d = dst + (size_t)e * C * R;
#pragma unroll
  for (int j = 0; j < 32; j += 8)
    tile[ty + j][tx] = s[(size_t)(r0 + ty + j) * C + (c0 + tx)];
  __syncthreads();
#pragma unroll
  for (int j = 0; j < 32; j += 8)
    d[(size_t)(c0 + ty + j) * R + (r0 + tx)] = f2bf(tile[tx][ty + j]);
}

// ---------------------------------------------------------------------------
extern "C" void kernel_launch(void* const* d_in, const int* in_sizes, int n_in,
                              void* d_out, int out_size, void* d_ws, size_t ws_size,
                              hipStream_t stream) {
  const float* x  = (const float*)d_in[0];
  const float* W1 = (const float*)d_in[1];
  const float* b1 = (const float*)d_in[2];
  const float* W2 = (const float*)d_in[3];
  const float* b2 = (const float*)d_in[4];
  const float* Wu = (const float*)d_in[5];
  const float* bu = (const float*)d_in[6];
  float* out = (float*)d_out;

  // workspace layout
  char* w = (char*)d_ws;
  unsigned short* xb  = (unsigned short*)w;  w += (size_t)BTOK * DD * 2;     // 16.78 MB
  unsigned short* W1T = (unsigned short*)w;  w += (size_t)EE * DD * FF * 2;  // 33.55 MB
  unsigned short* W2T = (unsigned short*)w;  w += (size_t)EE * FF * DD * 2;  // 33.55 MB
  float* c = (float*)w;                      w += (size_t)BTOK * EE * 4;     // 131 KB
  unsigned short* h = (unsigned short*)w;
  size_t used = (size_t)(w - (char*)d_ws);
  size_t hOne = (size_t)BTOK * FF * 2;        // 67.1 MB per expert slot

  // adaptive expert grouping: as many h slots as the workspace allows.
  // ws_size is constant across calls -> graph-safe.
  size_t avail = (ws_size > used) ? (ws_size - used) : 0;
  int hSlots = (int)(avail / hOne);
  if (hSlots < 1) hSlots = 1;
  if (hSlots > EE) hSlots = EE;

  // prep: bf16 x, transposed bf16 weights, u/c/b2-init
  cvt_kernel<<<(BTOK * DD / 4 + 255) / 256, 256, 0, stream>>>(x, xb, BTOK * DD / 4);
  tpose_kernel<<<dim3(FF / 32, DD / 32, EE), 256, 0, stream>>>(W1, W1T, DD, FF);
  tpose_kernel<<<dim3(DD / 32, FF / 32, EE), 256, 0, stream>>>(W2, W2T, FF, DD);
  u_kernel<<<BTOK, 256, 0, stream>>>(x, Wu, bu, b2, c, out);

  for (int g = 0; g < EE; g += hSlots) {
    int cnt = (EE - g < hSlots) ? (EE - g) : hSlots;
    gemm1_kernel<<<dim3(FF / 128, BTOK / 128, cnt), 256, 0, stream>>>(xb, W1T, b1, c, h, g);
    gemm2_kernel<<<dim3(DD / 128, BTOK / 128, 1), 256, 0, stream>>>(h, W2T, out, g, cnt);
  }
}